// Round 5
// baseline (197.696 us; speedup 1.0000x reference)
//
#include <hip/hip_runtime.h>
#include <hip/hip_bf16.h>
#include <hip/hip_cooperative_groups.h>
#include <math.h>

namespace cg = cooperative_groups;

#define NLVL 4
#define NSLOT 32768

typedef float f4 __attribute__((ext_vector_type(4)));

// ---------------------------------------------------------------------------
// K_h: h-row dots. grid = (128 rows, 4 levels), 256 threads.
// h = W1 @ x + b1 ; y = h * spec_wr  (irfft(n=1) keeps only the real part)
__global__ __launch_bounds__(256) void k_h(
    const float* __restrict__ s_t, const float* __restrict__ e_t,
    const float* __restrict__ ctx,
    const float* __restrict__ W1_0, const float* __restrict__ b1_0,
    const float* __restrict__ W1_r, const float* __restrict__ b1_r,
    const float* __restrict__ spec_wr, float* __restrict__ ybuf)
{
    const int row = blockIdx.x;
    const int ell = blockIdx.y;
    const int tid = threadIdx.x;
    const int d = (ell == 0) ? 2048 : 2560;
    const float* W1 = (ell == 0) ? W1_0 : (W1_r + (size_t)(ell - 1) * 128 * 2560);
    const float* b1 = (ell == 0) ? b1_0 : (b1_r + (ell - 1) * 128);
    const f4* wrow = (const f4*)(W1 + (size_t)row * d);

    float acc = 0.f;
    if (ell == 0) {
        for (int i4 = tid; i4 < 512; i4 += 256) {
            f4 w = wrow[i4];
            f4 x = (i4 < 256) ? ((const f4*)s_t)[i4]
                              : ((const f4*)e_t)[i4 - 256];
            acc += w.x * x.x + w.y * x.y + w.z * x.z + w.w * x.w;
        }
    } else {
        const f4* c4 = (const f4*)(ctx + (size_t)(ell - 1) * 512);
        for (int i4 = tid; i4 < 640; i4 += 256) {
            f4 w = wrow[i4];
            f4 x;
            if (i4 < 256)      x = ((const f4*)s_t)[i4];
            else if (i4 < 384) x = c4[i4 - 256];
            else               x = ((const f4*)e_t)[i4 - 384];
            acc += w.x * x.x + w.y * x.y + w.z * x.z + w.w * x.w;
        }
    }
    __shared__ float red[256];
    red[tid] = acc;
    __syncthreads();
    for (int off = 128; off > 0; off >>= 1) {
        if (tid < off) red[tid] += red[tid + off];
        __syncthreads();
    }
    if (tid == 0)
        ybuf[ell * 128 + row] = (red[0] + b1[row]) * spec_wr[ell * 128 + row];
}

// ---------------------------------------------------------------------------
// K_zvk: layernorm + gate + v/k projections. grid = (10, 4), 256 threads.
// Each block redundantly recomputes the (tiny) LN+gate from ybuf, then does
// 64 rows of Wv/Wk with 4 lanes/row.
__global__ __launch_bounds__(256) void k_zvk(
    const float* __restrict__ ybuf,
    const float* __restrict__ ln_g, const float* __restrict__ ln_b,
    const float* __restrict__ Wg, const float* __restrict__ bg,
    const float* __restrict__ decay,
    const float* __restrict__ Wv, const float* __restrict__ bv,
    const float* __restrict__ Wk, const float* __restrict__ bk,
    float* __restrict__ vvec, float* __restrict__ kvec,
    float* __restrict__ wgt, float* __restrict__ keepb)
{
    const int ell = blockIdx.y;
    const int t = threadIdx.x;
    __shared__ float red[128];
    __shared__ float sz[128];

    float y = 0.f;
    if (t < 128) { y = ybuf[ell * 128 + t]; red[t] = y; }
    __syncthreads();
    for (int off = 64; off > 0; off >>= 1) {
        if (t < off) red[t] += red[t + off];
        __syncthreads();
    }
    float mu = red[0] * (1.f / 128.f);
    __syncthreads();
    float dd = y - mu;
    if (t < 128) red[t] = dd * dd;
    __syncthreads();
    for (int off = 64; off > 0; off >>= 1) {
        if (t < off) red[t] += red[t + off];
        __syncthreads();
    }
    float rstd = rsqrtf(red[0] * (1.f / 128.f) + 1e-5f);
    __syncthreads();
    if (t < 128) sz[t] = dd * rstd * ln_g[ell * 128 + t] + ln_b[ell * 128 + t];
    __syncthreads();
    if (t < 128) red[t] = Wg[ell * 128 + t] * sz[t];
    __syncthreads();
    for (int off = 64; off > 0; off >>= 1) {
        if (t < off) red[t] += red[t + off];
        __syncthreads();
    }
    if (t == 0 && blockIdx.x == 0) {
        float g = 1.f / (1.f + expf(-(red[0] + bg[ell])));
        wgt[ell] = (g >= 0.1f) ? g : 0.f;
        keepb[ell] = 1.f - decay[ell];
    }

    // v/k projections: 64 rows per block, 4 lanes per row
    const int r = blockIdx.x * 64 + (t >> 2);  // 0..639
    const int lane = t & 3;
    const float* wrow;
    float bias;
    float* outp;
    bool is_v = (r < 512);
    if (is_v) {
        wrow = Wv + ((size_t)ell * 512 + r) * 128;
        bias = bv[ell * 512 + r];
        outp = vvec + ell * 512 + r;
    } else {
        int rk = r - 512;
        wrow = Wk + ((size_t)ell * 128 + rk) * 128;
        bias = bk[ell * 128 + rk];
        outp = kvec + ell * 128 + rk;
    }
    float a = 0.f;
    const f4* w4 = (const f4*)wrow + lane * 8;
    const float* z0 = sz + lane * 32;
    #pragma unroll
    for (int j = 0; j < 8; ++j) {
        f4 w = w4[j];
        a += w.x * z0[j * 4] + w.y * z0[j * 4 + 1] + w.z * z0[j * 4 + 2] + w.w * z0[j * 4 + 3];
    }
    a += __shfl_xor(a, 1);
    a += __shfl_xor(a, 2);
    if (lane == 0) {
        float val = a + bias;
        if (is_v) val = tanhf(val);
        *outp = val;
    }
}

// ---------------------------------------------------------------------------
// K_fused (cooperative): phase A = scores+exp for this block's 128 rows
// (kept in LDS) + per-block partial sum; grid.sync(); phase B = deterministic
// per-level denom reduce, then stream out = keep*[M|K] + c*[v|k].
// grid = 1024 blocks x 256 threads; block b owns global rows [b*128,(b+1)*128).
__global__ __launch_bounds__(256, 4) void k_fused(
    const float* __restrict__ M, const float* __restrict__ K_mem,
    const float* __restrict__ kvec, const float* __restrict__ vvec,
    const float* __restrict__ wgt, const float* __restrict__ keepb,
    float* __restrict__ partial, f4* __restrict__ out)
{
    const int b = blockIdx.x;
    const int tid = threadIdx.x;
    const int ell = b >> 8;          // 256 blocks per level
    const int r0 = b << 7;           // global row base

    __shared__ float sk[128];
    __shared__ float se[128];
    __shared__ float red[256];
    __shared__ f4 sv4[128];          // this level's v (512 floats)
    __shared__ f4 skv4[32];          // this level's k (128 floats)

    if (tid < 128) {
        sk[tid] = kvec[ell * 128 + tid];
        sv4[tid] = ((const f4*)vvec)[ell * 128 + tid];
    } else if (tid < 160) {
        skv4[tid - 128] = ((const f4*)kvec)[ell * 32 + (tid - 128)];
    }
    __syncthreads();

    // ---- phase A: scores for 128 rows, 16 lanes/row, 8 row-iters ----
    const int gid = tid >> 4, lane = tid & 15;
    const float* z0 = sk + lane * 8;
    const float scale = 0.08838834764831845f;   // 1/sqrt(128)
    float acc = 0.f;
    for (int it = 0; it < 8; ++it) {
        int rl = it * 16 + gid;                  // 0..127
        const f4* kr = (const f4*)K_mem + ((size_t)(r0 + rl)) * 32 + lane * 2;
        f4 wa = kr[0], wb = kr[1];
        float a = wa.x * z0[0] + wa.y * z0[1] + wa.z * z0[2] + wa.w * z0[3]
                + wb.x * z0[4] + wb.y * z0[5] + wb.z * z0[6] + wb.w * z0[7];
        #pragma unroll
        for (int m = 1; m < 16; m <<= 1) a += __shfl_xor(a, m);
        if (lane == 0) {
            float e = expf(a * scale);
            se[rl] = e;
            acc += e;
        }
    }
    red[tid] = acc;
    __syncthreads();
    for (int off = 128; off > 0; off >>= 1) {
        if (tid < off) red[tid] += red[tid + off];
        __syncthreads();
    }
    if (tid == 0) partial[b] = red[0];

    cg::this_grid().sync();

    // ---- phase B: level denom (deterministic tree over 256 partials) ----
    float p = partial[(ell << 8) + tid];
    red[tid] = p;
    __syncthreads();
    for (int off = 128; off > 0; off >>= 1) {
        if (tid < off) red[tid] += red[tid + off];
        __syncthreads();
    }
    const float scl = wgt[ell] / red[0];
    const float keep = keepb[ell];

    // precomputed per-thread (row-offset, j4) pattern within 1280-f4 chunks
    int dr[5], dj[5];
    #pragma unroll
    for (int k2 = 0; k2 < 5; ++k2) {
        int pos = tid + k2 * 256;
        dr[k2] = pos / 160;
        dj[k2] = pos - dr[k2] * 160;
    }

    const size_t ob = (size_t)r0 * 160;   // f4 base of this block's out chunk
    for (int mi = 0; mi < 16; ++mi) {     // 8 rows per macro-iter
        const int rowb = mi * 8;
        #pragma unroll
        for (int k2 = 0; k2 < 5; ++k2) {
            int rl = rowb + dr[k2];
            int j4 = dj[k2];
            float c = se[rl] * scl;
            size_t grow = (size_t)(r0 + rl);
            f4 o;
            if (j4 < 128) {
                f4 m = __builtin_nontemporal_load((const f4*)M + grow * 128 + j4);
                f4 vv = sv4[j4];
                o.x = keep * m.x + c * vv.x;
                o.y = keep * m.y + c * vv.y;
                o.z = keep * m.z + c * vv.z;
                o.w = keep * m.w + c * vv.w;
            } else {
                int jk = j4 - 128;
                f4 kk = ((const f4*)K_mem)[grow * 32 + jk];   // L2/L3-hot from phase A
                f4 kv = skv4[jk];
                o.x = keep * kk.x + c * kv.x;
                o.y = keep * kk.y + c * kv.y;
                o.z = keep * kk.z + c * kv.z;
                o.w = keep * kk.w + c * kv.w;
            }
            __builtin_nontemporal_store(o, out + ob + (size_t)mi * 1280 + tid + k2 * 256);
        }
    }
}

extern "C" void kernel_launch(void* const* d_in, const int* in_sizes, int n_in,
                              void* d_out, int out_size, void* d_ws, size_t ws_size,
                              hipStream_t stream) {
    const float* s_t    = (const float*)d_in[0];
    const float* e_t    = (const float*)d_in[1];
    const float* ctx    = (const float*)d_in[2];
    const float* M      = (const float*)d_in[3];
    const float* K_mem  = (const float*)d_in[4];
    const float* decay  = (const float*)d_in[5];
    const float* W1_0   = (const float*)d_in[6];
    const float* b1_0   = (const float*)d_in[7];
    const float* W1_r   = (const float*)d_in[8];
    const float* b1_r   = (const float*)d_in[9];
    const float* spec_wr= (const float*)d_in[10];
    // d_in[11] = spec_wi: unused — irfft(n=1) keeps only the real part
    const float* ln_g   = (const float*)d_in[12];
    const float* ln_b   = (const float*)d_in[13];
    const float* Wg     = (const float*)d_in[14];
    const float* bg     = (const float*)d_in[15];
    const float* Wv     = (const float*)d_in[16];
    const float* bv     = (const float*)d_in[17];
    const float* Wk     = (const float*)d_in[18];
    const float* bk     = (const float*)d_in[19];

    float* ws = (float*)d_ws;
    float* partial = ws;                 // 1024
    float* ybuf    = ws + 1024;          // 512
    float* kvec    = ws + 1536;          // 512
    float* vvec    = ws + 2048;          // 2048
    float* wgt     = ws + 4096;          // 4
    float* keepb   = ws + 4100;          // 4

    dim3 gh(128, NLVL);
    k_h<<<gh, 256, 0, stream>>>(s_t, e_t, ctx, W1_0, b1_0, W1_r, b1_r,
                                spec_wr, ybuf);

    dim3 gzvk(10, NLVL);
    k_zvk<<<gzvk, 256, 0, stream>>>(ybuf, ln_g, ln_b, Wg, bg, decay,
                                    Wv, bv, Wk, bk, vvec, kvec, wgt, keepb);

    f4* outp = (f4*)d_out;
    void* args[] = {(void*)&M, (void*)&K_mem, (void*)&kvec, (void*)&vvec,
                    (void*)&wgt, (void*)&keepb, (void*)&partial, (void*)&outp};
    hipLaunchCooperativeKernel((void*)k_fused, dim3(1024), dim3(256),
                               args, 0, stream);
}

// Round 6
// 148.301 us; speedup vs baseline: 1.3331x; 1.3331x over previous
//
#include <hip/hip_runtime.h>
#include <hip/hip_bf16.h>
#include <math.h>

#define NLVL 4
#define NSLOT 32768
#define SB 128          // score blocks per level

typedef float f4 __attribute__((ext_vector_type(4)));

// ---------------------------------------------------------------------------
// K_h: h-row dots. grid = (128 rows, 4 levels), 256 threads.
// h = W1 @ x + b1 ; y = h * spec_wr  (irfft(n=1) keeps only the real part)
__global__ __launch_bounds__(256) void k_h(
    const float* __restrict__ s_t, const float* __restrict__ e_t,
    const float* __restrict__ ctx,
    const float* __restrict__ W1_0, const float* __restrict__ b1_0,
    const float* __restrict__ W1_r, const float* __restrict__ b1_r,
    const float* __restrict__ spec_wr, float* __restrict__ ybuf)
{
    const int row = blockIdx.x;
    const int ell = blockIdx.y;
    const int tid = threadIdx.x;
    const int d = (ell == 0) ? 2048 : 2560;
    const float* W1 = (ell == 0) ? W1_0 : (W1_r + (size_t)(ell - 1) * 128 * 2560);
    const float* b1 = (ell == 0) ? b1_0 : (b1_r + (ell - 1) * 128);
    const f4* wrow = (const f4*)(W1 + (size_t)row * d);

    float acc = 0.f;
    if (ell == 0) {
        for (int i4 = tid; i4 < 512; i4 += 256) {
            f4 w = wrow[i4];
            f4 x = (i4 < 256) ? ((const f4*)s_t)[i4]
                              : ((const f4*)e_t)[i4 - 256];
            acc += w.x * x.x + w.y * x.y + w.z * x.z + w.w * x.w;
        }
    } else {
        const f4* c4 = (const f4*)(ctx + (size_t)(ell - 1) * 512);
        for (int i4 = tid; i4 < 640; i4 += 256) {
            f4 w = wrow[i4];
            f4 x;
            if (i4 < 256)      x = ((const f4*)s_t)[i4];
            else if (i4 < 384) x = c4[i4 - 256];
            else               x = ((const f4*)e_t)[i4 - 384];
            acc += w.x * x.x + w.y * x.y + w.z * x.z + w.w * x.w;
        }
    }
    __shared__ float red[256];
    red[tid] = acc;
    __syncthreads();
    for (int off = 128; off > 0; off >>= 1) {
        if (tid < off) red[tid] += red[tid + off];
        __syncthreads();
    }
    if (tid == 0)
        ybuf[ell * 128 + row] = (red[0] + b1[row]) * spec_wr[ell * 128 + row];
}

// ---------------------------------------------------------------------------
// K_zvk: layernorm + gate + v/k projections. grid = (10, 4), 256 threads.
__global__ __launch_bounds__(256) void k_zvk(
    const float* __restrict__ ybuf,
    const float* __restrict__ ln_g, const float* __restrict__ ln_b,
    const float* __restrict__ Wg, const float* __restrict__ bg,
    const float* __restrict__ decay,
    const float* __restrict__ Wv, const float* __restrict__ bv,
    const float* __restrict__ Wk, const float* __restrict__ bk,
    float* __restrict__ vvec, float* __restrict__ kvec,
    float* __restrict__ wgt, float* __restrict__ keepb)
{
    const int ell = blockIdx.y;
    const int t = threadIdx.x;
    __shared__ float red[128];
    __shared__ float sz[128];

    float y = 0.f;
    if (t < 128) { y = ybuf[ell * 128 + t]; red[t] = y; }
    __syncthreads();
    for (int off = 64; off > 0; off >>= 1) {
        if (t < off) red[t] += red[t + off];
        __syncthreads();
    }
    float mu = red[0] * (1.f / 128.f);
    __syncthreads();
    float dd = y - mu;
    if (t < 128) red[t] = dd * dd;
    __syncthreads();
    for (int off = 64; off > 0; off >>= 1) {
        if (t < off) red[t] += red[t + off];
        __syncthreads();
    }
    float rstd = rsqrtf(red[0] * (1.f / 128.f) + 1e-5f);
    __syncthreads();
    if (t < 128) sz[t] = dd * rstd * ln_g[ell * 128 + t] + ln_b[ell * 128 + t];
    __syncthreads();
    if (t < 128) red[t] = Wg[ell * 128 + t] * sz[t];
    __syncthreads();
    for (int off = 64; off > 0; off >>= 1) {
        if (t < off) red[t] += red[t + off];
        __syncthreads();
    }
    if (t == 0 && blockIdx.x == 0) {
        float g = 1.f / (1.f + expf(-(red[0] + bg[ell])));
        wgt[ell] = (g >= 0.1f) ? g : 0.f;
        keepb[ell] = 1.f - decay[ell];
    }

    // v/k projections: 64 rows per block, 4 lanes per row
    const int r = blockIdx.x * 64 + (t >> 2);  // 0..639
    const int lane = t & 3;
    const float* wrow;
    float bias;
    float* outp;
    bool is_v = (r < 512);
    if (is_v) {
        wrow = Wv + ((size_t)ell * 512 + r) * 128;
        bias = bv[ell * 512 + r];
        outp = vvec + ell * 512 + r;
    } else {
        int rk = r - 512;
        wrow = Wk + ((size_t)ell * 128 + rk) * 128;
        bias = bk[ell * 128 + rk];
        outp = kvec + ell * 128 + rk;
    }
    float a = 0.f;
    const f4* w4 = (const f4*)wrow + lane * 8;
    const float* z0 = sz + lane * 32;
    #pragma unroll
    for (int j = 0; j < 8; ++j) {
        f4 w = w4[j];
        a += w.x * z0[j * 4] + w.y * z0[j * 4 + 1] + w.z * z0[j * 4 + 2] + w.w * z0[j * 4 + 3];
    }
    a += __shfl_xor(a, 1);
    a += __shfl_xor(a, 2);
    if (lane == 0) {
        float val = a + bias;
        if (is_v) val = tanhf(val);
        *outp = val;
    }
}

// ---------------------------------------------------------------------------
// K_scores: e = exp(score), per-block partial sums. grid = (SB, 4), 256 thr.
__global__ __launch_bounds__(256) void k_scores(
    const float* __restrict__ K_mem, const float* __restrict__ kvec,
    float* __restrict__ expsc, float* __restrict__ partial)
{
    const int ell = blockIdx.y;
    const int tid = threadIdx.x;
    __shared__ float sk[128];
    __shared__ float red[256];
    if (tid < 128) sk[tid] = kvec[ell * 128 + tid];
    __syncthreads();

    const int n0 = blockIdx.x * (NSLOT / SB);   // 256 rows per block
    const int gid = tid >> 4, lane = tid & 15;
    const float* z0 = sk + lane * 8;
    const float scale = 0.08838834764831845f;   // 1/sqrt(128)
    float acc = 0.f;
    for (int it = 0; it < 16; ++it) {
        int n = n0 + it * 16 + gid;
        const f4* kr = (const f4*)(K_mem + ((size_t)ell * NSLOT + n) * 128) + lane * 2;
        f4 wa = kr[0], wb = kr[1];
        float a = wa.x * z0[0] + wa.y * z0[1] + wa.z * z0[2] + wa.w * z0[3]
                + wb.x * z0[4] + wb.y * z0[5] + wb.z * z0[6] + wb.w * z0[7];
        #pragma unroll
        for (int m = 1; m < 16; m <<= 1) a += __shfl_xor(a, m);
        if (lane == 0) {
            float e = expf(a * scale);
            expsc[(size_t)ell * NSLOT + n] = e;
            acc += e;
        }
    }
    red[tid] = acc;
    __syncthreads();
    for (int off = 128; off > 0; off >>= 1) {
        if (tid < off) red[tid] += red[tid + off];
        __syncthreads();
    }
    if (tid == 0) partial[ell * SB + blockIdx.x] = red[0];
}

// ---------------------------------------------------------------------------
// K_write2: block owns 64 contiguous rows (2048 blocks x 256 threads).
// Denom reduced per block (deterministic), 64 row-coefs staged in LDS,
// precomputed (row,col) pattern — no per-element division.
__global__ __launch_bounds__(256) void k_write2(
    const float* __restrict__ M, const float* __restrict__ K_mem,
    const float* __restrict__ expsc, const float* __restrict__ partial,
    const float* __restrict__ wgt, const float* __restrict__ keepb,
    const float* __restrict__ vvec, const float* __restrict__ kvec,
    f4* __restrict__ out)
{
    const int b = blockIdx.x;          // 2048
    const int tid = threadIdx.x;
    const int ell = b >> 9;            // 512 blocks per level
    const int r0 = b << 6;             // 64 rows per block (global row)

    __shared__ float scoef[64];
    __shared__ f4 sv4[128];            // level's v (512 floats)
    __shared__ f4 skv4[32];            // level's k (128 floats)
    __shared__ float red[128];

    if (tid < 128) {
        sv4[tid] = ((const f4*)vvec)[ell * 128 + tid];
        red[tid] = partial[ell * SB + tid];
    } else if (tid < 160) {
        skv4[tid - 128] = ((const f4*)kvec)[ell * 32 + (tid - 128)];
    }
    __syncthreads();
    for (int off = 64; off > 0; off >>= 1) {
        if (tid < off) red[tid] += red[tid + off];
        __syncthreads();
    }
    const float scl = wgt[ell] / red[0];
    const float keep = keepb[ell];
    if (tid < 64) scoef[tid] = expsc[r0 + tid] * scl;
    __syncthreads();

    // fixed per-thread pattern over a 1280-f4 (8-row) tile
    int dr[5], dj[5];
    #pragma unroll
    for (int k2 = 0; k2 < 5; ++k2) {
        int pos = tid + k2 * 256;
        dr[k2] = pos / 160;            // compile-time-ish: unrolled, const divisor
        dj[k2] = pos - dr[k2] * 160;
    }

    const size_t ob = (size_t)r0 * 160;
    for (int mi = 0; mi < 8; ++mi) {   // 8 tiles x 8 rows = 64 rows
        #pragma unroll
        for (int k2 = 0; k2 < 5; ++k2) {
            int rl = mi * 8 + dr[k2];
            float c = scoef[rl];
            size_t grow = (size_t)(r0 + rl);
            f4 o;
            if (dj[k2] < 128) {
                f4 m = ((const f4*)M)[grow * 128 + dj[k2]];
                f4 vv = sv4[dj[k2]];
                o.x = keep * m.x + c * vv.x;
                o.y = keep * m.y + c * vv.y;
                o.z = keep * m.z + c * vv.z;
                o.w = keep * m.w + c * vv.w;
            } else {
                int jk = dj[k2] - 128;
                f4 kk = ((const f4*)K_mem)[grow * 32 + jk];
                f4 kv = skv4[jk];
                o.x = keep * kk.x + c * kv.x;
                o.y = keep * kk.y + c * kv.y;
                o.z = keep * kk.z + c * kv.z;
                o.w = keep * kk.w + c * kv.w;
            }
            __builtin_nontemporal_store(o, out + ob + mi * 1280 + tid + k2 * 256);
        }
    }
}

extern "C" void kernel_launch(void* const* d_in, const int* in_sizes, int n_in,
                              void* d_out, int out_size, void* d_ws, size_t ws_size,
                              hipStream_t stream) {
    const float* s_t    = (const float*)d_in[0];
    const float* e_t    = (const float*)d_in[1];
    const float* ctx    = (const float*)d_in[2];
    const float* M      = (const float*)d_in[3];
    const float* K_mem  = (const float*)d_in[4];
    const float* decay  = (const float*)d_in[5];
    const float* W1_0   = (const float*)d_in[6];
    const float* b1_0   = (const float*)d_in[7];
    const float* W1_r   = (const float*)d_in[8];
    const float* b1_r   = (const float*)d_in[9];
    const float* spec_wr= (const float*)d_in[10];
    // d_in[11] = spec_wi: unused — irfft(n=1) keeps only the real part
    const float* ln_g   = (const float*)d_in[12];
    const float* ln_b   = (const float*)d_in[13];
    const float* Wg     = (const float*)d_in[14];
    const float* bg     = (const float*)d_in[15];
    const float* Wv     = (const float*)d_in[16];
    const float* bv     = (const float*)d_in[17];
    const float* Wk     = (const float*)d_in[18];
    const float* bk     = (const float*)d_in[19];

    float* ws = (float*)d_ws;
    float* expsc   = ws;                 // L*N            = 131072
    float* partial = ws + 131072;        // L*SB           = 512
    float* ybuf    = ws + 131584;        // 512
    float* kvec    = ws + 132096;        // 512
    float* vvec    = ws + 132608;        // 2048
    float* wgt     = ws + 134656;        // 4
    float* keepb   = ws + 134660;        // 4

    dim3 gh(128, NLVL);
    k_h<<<gh, 256, 0, stream>>>(s_t, e_t, ctx, W1_0, b1_0, W1_r, b1_r,
                                spec_wr, ybuf);

    dim3 gzvk(10, NLVL);
    k_zvk<<<gzvk, 256, 0, stream>>>(ybuf, ln_g, ln_b, Wg, bg, decay,
                                    Wv, bv, Wk, bk, vvec, kvec, wgt, keepb);

    dim3 gs(SB, NLVL);
    k_scores<<<gs, 256, 0, stream>>>(K_mem, kvec, expsc, partial);

    k_write2<<<2048, 256, 0, stream>>>(M, K_mem, expsc, partial, wgt, keepb,
                                       vvec, kvec, (f4*)d_out);
}

// Round 7
// 147.899 us; speedup vs baseline: 1.3367x; 1.0027x over previous
//
#include <hip/hip_runtime.h>
#include <hip/hip_bf16.h>
#include <math.h>

#define NLVL 4
#define NSLOT 32768
#define SB 128          // score blocks per level

typedef float f4 __attribute__((ext_vector_type(4)));

// ---------------------------------------------------------------------------
// K_h: h-row dots. grid = (128 rows, 4 levels), 256 threads.
// h = W1 @ x + b1 ; y = h * spec_wr  (irfft(n=1) keeps only the real part)
__global__ __launch_bounds__(256) void k_h(
    const float* __restrict__ s_t, const float* __restrict__ e_t,
    const float* __restrict__ ctx,
    const float* __restrict__ W1_0, const float* __restrict__ b1_0,
    const float* __restrict__ W1_r, const float* __restrict__ b1_r,
    const float* __restrict__ spec_wr, float* __restrict__ ybuf)
{
    const int row = blockIdx.x;
    const int ell = blockIdx.y;
    const int tid = threadIdx.x;
    const int d = (ell == 0) ? 2048 : 2560;
    const float* W1 = (ell == 0) ? W1_0 : (W1_r + (size_t)(ell - 1) * 128 * 2560);
    const float* b1 = (ell == 0) ? b1_0 : (b1_r + (ell - 1) * 128);
    const f4* wrow = (const f4*)(W1 + (size_t)row * d);

    float acc = 0.f;
    if (ell == 0) {
        for (int i4 = tid; i4 < 512; i4 += 256) {
            f4 w = wrow[i4];
            f4 x = (i4 < 256) ? ((const f4*)s_t)[i4]
                              : ((const f4*)e_t)[i4 - 256];
            acc += w.x * x.x + w.y * x.y + w.z * x.z + w.w * x.w;
        }
    } else {
        const f4* c4 = (const f4*)(ctx + (size_t)(ell - 1) * 512);
        for (int i4 = tid; i4 < 640; i4 += 256) {
            f4 w = wrow[i4];
            f4 x;
            if (i4 < 256)      x = ((const f4*)s_t)[i4];
            else if (i4 < 384) x = c4[i4 - 256];
            else               x = ((const f4*)e_t)[i4 - 384];
            acc += w.x * x.x + w.y * x.y + w.z * x.z + w.w * x.w;
        }
    }
    __shared__ float red[256];
    red[tid] = acc;
    __syncthreads();
    for (int off = 128; off > 0; off >>= 1) {
        if (tid < off) red[tid] += red[tid + off];
        __syncthreads();
    }
    if (tid == 0)
        ybuf[ell * 128 + row] = (red[0] + b1[row]) * spec_wr[ell * 128 + row];
}

// ---------------------------------------------------------------------------
// K_zvk: layernorm + gate + v/k projections. grid = (10, 4), 256 threads.
__global__ __launch_bounds__(256) void k_zvk(
    const float* __restrict__ ybuf,
    const float* __restrict__ ln_g, const float* __restrict__ ln_b,
    const float* __restrict__ Wg, const float* __restrict__ bg,
    const float* __restrict__ decay,
    const float* __restrict__ Wv, const float* __restrict__ bv,
    const float* __restrict__ Wk, const float* __restrict__ bk,
    float* __restrict__ vvec, float* __restrict__ kvec,
    float* __restrict__ wgt, float* __restrict__ keepb)
{
    const int ell = blockIdx.y;
    const int t = threadIdx.x;
    __shared__ float red[128];
    __shared__ float sz[128];

    float y = 0.f;
    if (t < 128) { y = ybuf[ell * 128 + t]; red[t] = y; }
    __syncthreads();
    for (int off = 64; off > 0; off >>= 1) {
        if (t < off) red[t] += red[t + off];
        __syncthreads();
    }
    float mu = red[0] * (1.f / 128.f);
    __syncthreads();
    float dd = y - mu;
    if (t < 128) red[t] = dd * dd;
    __syncthreads();
    for (int off = 64; off > 0; off >>= 1) {
        if (t < off) red[t] += red[t + off];
        __syncthreads();
    }
    float rstd = rsqrtf(red[0] * (1.f / 128.f) + 1e-5f);
    __syncthreads();
    if (t < 128) sz[t] = dd * rstd * ln_g[ell * 128 + t] + ln_b[ell * 128 + t];
    __syncthreads();
    if (t < 128) red[t] = Wg[ell * 128 + t] * sz[t];
    __syncthreads();
    for (int off = 64; off > 0; off >>= 1) {
        if (t < off) red[t] += red[t + off];
        __syncthreads();
    }
    if (t == 0 && blockIdx.x == 0) {
        float g = 1.f / (1.f + expf(-(red[0] + bg[ell])));
        wgt[ell] = (g >= 0.1f) ? g : 0.f;
        keepb[ell] = 1.f - decay[ell];
    }

    // v/k projections: 64 rows per block, 4 lanes per row
    const int r = blockIdx.x * 64 + (t >> 2);  // 0..639
    const int lane = t & 3;
    const float* wrow;
    float bias;
    float* outp;
    bool is_v = (r < 512);
    if (is_v) {
        wrow = Wv + ((size_t)ell * 512 + r) * 128;
        bias = bv[ell * 512 + r];
        outp = vvec + ell * 512 + r;
    } else {
        int rk = r - 512;
        wrow = Wk + ((size_t)ell * 128 + rk) * 128;
        bias = bk[ell * 128 + rk];
        outp = kvec + ell * 128 + rk;
    }
    float a = 0.f;
    const f4* w4 = (const f4*)wrow + lane * 8;
    const float* z0 = sz + lane * 32;
    #pragma unroll
    for (int j = 0; j < 8; ++j) {
        f4 w = w4[j];
        a += w.x * z0[j * 4] + w.y * z0[j * 4 + 1] + w.z * z0[j * 4 + 2] + w.w * z0[j * 4 + 3];
    }
    a += __shfl_xor(a, 1);
    a += __shfl_xor(a, 2);
    if (lane == 0) {
        float val = a + bias;
        if (is_v) val = tanhf(val);
        *outp = val;
    }
}

// ---------------------------------------------------------------------------
// K_scores: e = exp(score), per-block partial sums. grid = (SB, 4), 256 thr.
// Normal (caching) loads — K_mem (64 MB total) should become L3-resident
// for k_write3's re-read.
__global__ __launch_bounds__(256) void k_scores(
    const float* __restrict__ K_mem, const float* __restrict__ kvec,
    float* __restrict__ expsc, float* __restrict__ partial)
{
    const int ell = blockIdx.y;
    const int tid = threadIdx.x;
    __shared__ float sk[128];
    __shared__ float red[256];
    if (tid < 128) sk[tid] = kvec[ell * 128 + tid];
    __syncthreads();

    const int n0 = blockIdx.x * (NSLOT / SB);   // 256 rows per block
    const int gid = tid >> 4, lane = tid & 15;
    const float* z0 = sk + lane * 8;
    const float scale = 0.08838834764831845f;   // 1/sqrt(128)
    float acc = 0.f;
    for (int it = 0; it < 16; ++it) {
        int n = n0 + it * 16 + gid;
        const f4* kr = (const f4*)(K_mem + ((size_t)ell * NSLOT + n) * 128) + lane * 2;
        f4 wa = kr[0], wb = kr[1];
        float a = wa.x * z0[0] + wa.y * z0[1] + wa.z * z0[2] + wa.w * z0[3]
                + wb.x * z0[4] + wb.y * z0[5] + wb.z * z0[6] + wb.w * z0[7];
        #pragma unroll
        for (int m = 1; m < 16; m <<= 1) a += __shfl_xor(a, m);
        if (lane == 0) {
            float e = expf(a * scale);
            expsc[(size_t)ell * NSLOT + n] = e;
            acc += e;
        }
    }
    red[tid] = acc;
    __syncthreads();
    for (int off = 128; off > 0; off >>= 1) {
        if (tid < off) red[tid] += red[tid + off];
        __syncthreads();
    }
    if (tid == 0) partial[ell * SB + blockIdx.x] = red[0];
}

// ---------------------------------------------------------------------------
// K_write3: block owns 64 contiguous rows (2048 blocks x 256 threads).
// nt loads on M (don't pollute L3 -> K_mem stays resident), cached loads on
// K_mem (L3-hot from k_scores), nt stores on out. Two-phase inner loop:
// batch 5 loads, then 5 compute+store.
__global__ __launch_bounds__(256) void k_write3(
    const float* __restrict__ M, const float* __restrict__ K_mem,
    const float* __restrict__ expsc, const float* __restrict__ partial,
    const float* __restrict__ wgt, const float* __restrict__ keepb,
    const float* __restrict__ vvec, const float* __restrict__ kvec,
    f4* __restrict__ out)
{
    const int b = blockIdx.x;          // 2048
    const int tid = threadIdx.x;
    const int ell = b >> 9;            // 512 blocks per level
    const int r0 = b << 6;             // 64 rows per block (global row)

    __shared__ float scoef[64];
    __shared__ f4 sv4[128];            // level's v (512 floats)
    __shared__ f4 skv4[32];            // level's k (128 floats)
    __shared__ float red[128];

    if (tid < 128) {
        sv4[tid] = ((const f4*)vvec)[ell * 128 + tid];
        red[tid] = partial[ell * SB + tid];
    } else if (tid < 160) {
        skv4[tid - 128] = ((const f4*)kvec)[ell * 32 + (tid - 128)];
    }
    __syncthreads();
    for (int off = 64; off > 0; off >>= 1) {
        if (tid < off) red[tid] += red[tid + off];
        __syncthreads();
    }
    const float scl = wgt[ell] / red[0];
    const float keep = keepb[ell];
    if (tid < 64) scoef[tid] = expsc[r0 + tid] * scl;
    __syncthreads();

    // fixed per-thread pattern over a 1280-f4 (8-row) tile
    int dr[5], dj[5];
    bool ism[5];
    #pragma unroll
    for (int k2 = 0; k2 < 5; ++k2) {
        int pos = tid + k2 * 256;
        dr[k2] = pos / 160;
        dj[k2] = pos - dr[k2] * 160;
        ism[k2] = (dj[k2] < 128);
    }

    const size_t ob = (size_t)r0 * 160;
    for (int mi = 0; mi < 8; ++mi) {   // 8 tiles x 8 rows = 64 rows
        f4 in[5];
        // phase 1: issue all loads
        #pragma unroll
        for (int k2 = 0; k2 < 5; ++k2) {
            size_t grow = (size_t)(r0 + mi * 8 + dr[k2]);
            if (ism[k2]) {
                in[k2] = __builtin_nontemporal_load((const f4*)M + grow * 128 + dj[k2]);
            } else {
                in[k2] = ((const f4*)K_mem)[grow * 32 + (dj[k2] - 128)];
            }
        }
        // phase 2: compute + store
        #pragma unroll
        for (int k2 = 0; k2 < 5; ++k2) {
            float c = scoef[mi * 8 + dr[k2]];
            f4 src = ism[k2] ? sv4[dj[k2]] : skv4[dj[k2] - 128];
            f4 o;
            o.x = keep * in[k2].x + c * src.x;
            o.y = keep * in[k2].y + c * src.y;
            o.z = keep * in[k2].z + c * src.z;
            o.w = keep * in[k2].w + c * src.w;
            __builtin_nontemporal_store(o, out + ob + mi * 1280 + tid + k2 * 256);
        }
    }
}

extern "C" void kernel_launch(void* const* d_in, const int* in_sizes, int n_in,
                              void* d_out, int out_size, void* d_ws, size_t ws_size,
                              hipStream_t stream) {
    const float* s_t    = (const float*)d_in[0];
    const float* e_t    = (const float*)d_in[1];
    const float* ctx    = (const float*)d_in[2];
    const float* M      = (const float*)d_in[3];
    const float* K_mem  = (const float*)d_in[4];
    const float* decay  = (const float*)d_in[5];
    const float* W1_0   = (const float*)d_in[6];
    const float* b1_0   = (const float*)d_in[7];
    const float* W1_r   = (const float*)d_in[8];
    const float* b1_r   = (const float*)d_in[9];
    const float* spec_wr= (const float*)d_in[10];
    // d_in[11] = spec_wi: unused — irfft(n=1) keeps only the real part
    const float* ln_g   = (const float*)d_in[12];
    const float* ln_b   = (const float*)d_in[13];
    const float* Wg     = (const float*)d_in[14];
    const float* bg     = (const float*)d_in[15];
    const float* Wv     = (const float*)d_in[16];
    const float* bv     = (const float*)d_in[17];
    const float* Wk     = (const float*)d_in[18];
    const float* bk     = (const float*)d_in[19];

    float* ws = (float*)d_ws;
    float* expsc   = ws;                 // L*N            = 131072
    float* partial = ws + 131072;        // L*SB           = 512
    float* ybuf    = ws + 131584;        // 512
    float* kvec    = ws + 132096;        // 512
    float* vvec    = ws + 132608;        // 2048
    float* wgt     = ws + 134656;        // 4
    float* keepb   = ws + 134660;        // 4

    dim3 gh(128, NLVL);
    k_h<<<gh, 256, 0, stream>>>(s_t, e_t, ctx, W1_0, b1_0, W1_r, b1_r,
                                spec_wr, ybuf);

    dim3 gzvk(10, NLVL);
    k_zvk<<<gzvk, 256, 0, stream>>>(ybuf, ln_g, ln_b, Wg, bg, decay,
                                    Wv, bv, Wk, bk, vvec, kvec, wgt, keepb);

    dim3 gs(SB, NLVL);
    k_scores<<<gs, 256, 0, stream>>>(K_mem, kvec, expsc, partial);

    k_write3<<<2048, 256, 0, stream>>>(M, K_mem, expsc, partial, wgt, keepb,
                                       vvec, kvec, (f4*)d_out);
}

// Round 8
// 143.048 us; speedup vs baseline: 1.3820x; 1.0339x over previous
//
#include <hip/hip_runtime.h>
#include <hip/hip_bf16.h>
#include <math.h>

#define NLVL 4
#define NSLOT 32768
#define SB 512          // score blocks per level (64 rows each)

typedef float f4 __attribute__((ext_vector_type(4)));

// ---------------------------------------------------------------------------
// K_h: h-row dots. grid = (128 rows, 4 levels), 256 threads.
// h = W1 @ x + b1 ; y = h * spec_wr  (irfft(n=1) keeps only the real part)
__global__ __launch_bounds__(256) void k_h(
    const float* __restrict__ s_t, const float* __restrict__ e_t,
    const float* __restrict__ ctx,
    const float* __restrict__ W1_0, const float* __restrict__ b1_0,
    const float* __restrict__ W1_r, const float* __restrict__ b1_r,
    const float* __restrict__ spec_wr, float* __restrict__ ybuf)
{
    const int row = blockIdx.x;
    const int ell = blockIdx.y;
    const int tid = threadIdx.x;
    const int d = (ell == 0) ? 2048 : 2560;
    const float* W1 = (ell == 0) ? W1_0 : (W1_r + (size_t)(ell - 1) * 128 * 2560);
    const float* b1 = (ell == 0) ? b1_0 : (b1_r + (ell - 1) * 128);
    const f4* wrow = (const f4*)(W1 + (size_t)row * d);

    float acc = 0.f;
    if (ell == 0) {
        for (int i4 = tid; i4 < 512; i4 += 256) {
            f4 w = wrow[i4];
            f4 x = (i4 < 256) ? ((const f4*)s_t)[i4]
                              : ((const f4*)e_t)[i4 - 256];
            acc += w.x * x.x + w.y * x.y + w.z * x.z + w.w * x.w;
        }
    } else {
        const f4* c4 = (const f4*)(ctx + (size_t)(ell - 1) * 512);
        for (int i4 = tid; i4 < 640; i4 += 256) {
            f4 w = wrow[i4];
            f4 x;
            if (i4 < 256)      x = ((const f4*)s_t)[i4];
            else if (i4 < 384) x = c4[i4 - 256];
            else               x = ((const f4*)e_t)[i4 - 384];
            acc += w.x * x.x + w.y * x.y + w.z * x.z + w.w * x.w;
        }
    }
    __shared__ float red[256];
    red[tid] = acc;
    __syncthreads();
    for (int off = 128; off > 0; off >>= 1) {
        if (tid < off) red[tid] += red[tid + off];
        __syncthreads();
    }
    if (tid == 0)
        ybuf[ell * 128 + row] = (red[0] + b1[row]) * spec_wr[ell * 128 + row];
}

// ---------------------------------------------------------------------------
// K_zvk: layernorm + gate + v/k projections. grid = (10, 4), 256 threads.
__global__ __launch_bounds__(256) void k_zvk(
    const float* __restrict__ ybuf,
    const float* __restrict__ ln_g, const float* __restrict__ ln_b,
    const float* __restrict__ Wg, const float* __restrict__ bg,
    const float* __restrict__ decay,
    const float* __restrict__ Wv, const float* __restrict__ bv,
    const float* __restrict__ Wk, const float* __restrict__ bk,
    float* __restrict__ vvec, float* __restrict__ kvec,
    float* __restrict__ wgt, float* __restrict__ keepb)
{
    const int ell = blockIdx.y;
    const int t = threadIdx.x;
    __shared__ float red[128];
    __shared__ float sz[128];

    float y = 0.f;
    if (t < 128) { y = ybuf[ell * 128 + t]; red[t] = y; }
    __syncthreads();
    for (int off = 64; off > 0; off >>= 1) {
        if (t < off) red[t] += red[t + off];
        __syncthreads();
    }
    float mu = red[0] * (1.f / 128.f);
    __syncthreads();
    float dd = y - mu;
    if (t < 128) red[t] = dd * dd;
    __syncthreads();
    for (int off = 64; off > 0; off >>= 1) {
        if (t < off) red[t] += red[t + off];
        __syncthreads();
    }
    float rstd = rsqrtf(red[0] * (1.f / 128.f) + 1e-5f);
    __syncthreads();
    if (t < 128) sz[t] = dd * rstd * ln_g[ell * 128 + t] + ln_b[ell * 128 + t];
    __syncthreads();
    if (t < 128) red[t] = Wg[ell * 128 + t] * sz[t];
    __syncthreads();
    for (int off = 64; off > 0; off >>= 1) {
        if (t < off) red[t] += red[t + off];
        __syncthreads();
    }
    if (t == 0 && blockIdx.x == 0) {
        float g = 1.f / (1.f + expf(-(red[0] + bg[ell])));
        wgt[ell] = (g >= 0.1f) ? g : 0.f;
        keepb[ell] = 1.f - decay[ell];
    }

    // v/k projections: 64 rows per block, 4 lanes per row
    const int r = blockIdx.x * 64 + (t >> 2);  // 0..639
    const int lane = t & 3;
    const float* wrow;
    float bias;
    float* outp;
    bool is_v = (r < 512);
    if (is_v) {
        wrow = Wv + ((size_t)ell * 512 + r) * 128;
        bias = bv[ell * 512 + r];
        outp = vvec + ell * 512 + r;
    } else {
        int rk = r - 512;
        wrow = Wk + ((size_t)ell * 128 + rk) * 128;
        bias = bk[ell * 128 + rk];
        outp = kvec + ell * 128 + rk;
    }
    float a = 0.f;
    const f4* w4 = (const f4*)wrow + lane * 8;
    const float* z0 = sz + lane * 32;
    #pragma unroll
    for (int j = 0; j < 8; ++j) {
        f4 w = w4[j];
        a += w.x * z0[j * 4] + w.y * z0[j * 4 + 1] + w.z * z0[j * 4 + 2] + w.w * z0[j * 4 + 3];
    }
    a += __shfl_xor(a, 1);
    a += __shfl_xor(a, 2);
    if (lane == 0) {
        float val = a + bias;
        if (is_v) val = tanhf(val);
        *outp = val;
    }
}

// ---------------------------------------------------------------------------
// K_scores: e = exp(score), per-block partial sums. grid = (SB=512, 4),
// 256 threads, 64 rows/block -> 2048 blocks (32 waves/CU) with 2-row ILP.
__global__ __launch_bounds__(256) void k_scores(
    const float* __restrict__ K_mem, const float* __restrict__ kvec,
    float* __restrict__ expsc, float* __restrict__ partial)
{
    const int ell = blockIdx.y;
    const int tid = threadIdx.x;
    __shared__ float sk[128];
    __shared__ float red[256];
    if (tid < 128) sk[tid] = kvec[ell * 128 + tid];
    __syncthreads();

    const int n0 = blockIdx.x * 64;             // 64 rows per block
    const int gid = tid >> 4, lane = tid & 15;
    const float* z0 = sk + lane * 8;
    const float scale = 0.08838834764831845f;   // 1/sqrt(128)
    float acc = 0.f;
    #pragma unroll
    for (int it = 0; it < 2; ++it) {
        int nA = n0 + it * 32 + gid;
        int nB = nA + 16;
        const f4* ka = (const f4*)K_mem + ((size_t)ell * NSLOT + nA) * 32 + lane * 2;
        const f4* kb = (const f4*)K_mem + ((size_t)ell * NSLOT + nB) * 32 + lane * 2;
        f4 a0 = ka[0], a1 = ka[1];
        f4 b0 = kb[0], b1 = kb[1];
        float a = a0.x * z0[0] + a0.y * z0[1] + a0.z * z0[2] + a0.w * z0[3]
                + a1.x * z0[4] + a1.y * z0[5] + a1.z * z0[6] + a1.w * z0[7];
        float b = b0.x * z0[0] + b0.y * z0[1] + b0.z * z0[2] + b0.w * z0[3]
                + b1.x * z0[4] + b1.y * z0[5] + b1.z * z0[6] + b1.w * z0[7];
        #pragma unroll
        for (int m = 1; m < 16; m <<= 1) { a += __shfl_xor(a, m); b += __shfl_xor(b, m); }
        if (lane == 0) {
            float ea = expf(a * scale);
            float eb = expf(b * scale);
            expsc[(size_t)ell * NSLOT + nA] = ea;
            expsc[(size_t)ell * NSLOT + nB] = eb;
            acc += ea + eb;
        }
    }
    red[tid] = acc;
    __syncthreads();
    for (int off = 128; off > 0; off >>= 1) {
        if (tid < off) red[tid] += red[tid + off];
        __syncthreads();
    }
    if (tid == 0) partial[ell * SB + blockIdx.x] = red[0];
}

// ---------------------------------------------------------------------------
// K_write4: block owns 64 contiguous rows (2048 blocks x 256 threads).
// Phase-split (M-half then K-half): every wave uniform, branch-free,
// shift addressing, 4-deep load batches. nt loads on M, nt stores on out.
__global__ __launch_bounds__(256) void k_write4(
    const float* __restrict__ M, const float* __restrict__ K_mem,
    const float* __restrict__ expsc, const float* __restrict__ partial,
    const float* __restrict__ wgt, const float* __restrict__ keepb,
    const float* __restrict__ vvec, const float* __restrict__ kvec,
    f4* __restrict__ out)
{
    const int b = blockIdx.x;          // 2048
    const int tid = threadIdx.x;
    const int ell = b >> 9;            // 512 blocks per level
    const int r0 = b << 6;             // 64 rows per block (global row)

    __shared__ float scoef[64];
    __shared__ f4 sv4[128];            // level's v (512 floats)
    __shared__ f4 skv4[32];            // level's k (128 floats)
    __shared__ float red[256];

    if (tid < 128) sv4[tid] = ((const f4*)vvec)[ell * 128 + tid];
    if (tid < 32)  skv4[tid] = ((const f4*)kvec)[ell * 32 + tid];
    red[tid] = partial[ell * SB + tid] + partial[ell * SB + 256 + tid];
    __syncthreads();
    for (int off = 128; off > 0; off >>= 1) {
        if (tid < off) red[tid] += red[tid + off];
        __syncthreads();
    }
    const float scl = wgt[ell] / red[0];
    const float keep = keepb[ell];
    if (tid < 64) scoef[tid] = expsc[r0 + tid] * scl;
    __syncthreads();

    const size_t obase = (size_t)r0 * 160;
    const f4* Mb = (const f4*)M + (size_t)r0 * 128;
    const f4* Kb = (const f4*)K_mem + (size_t)r0 * 32;

    // ---- M phase: 64 rows x 128 f4 = 8192 f4, 4-deep batches ----
    for (int t8 = 0; t8 < 8; ++t8) {
        f4 in[4];
        int idx[4];
        #pragma unroll
        for (int j = 0; j < 4; ++j) {
            idx[j] = t8 * 1024 + j * 256 + tid;
            in[j] = __builtin_nontemporal_load(Mb + idx[j]);
        }
        #pragma unroll
        for (int j = 0; j < 4; ++j) {
            int row = idx[j] >> 7, col = idx[j] & 127;
            float c = scoef[row];
            f4 s = sv4[col];
            f4 o;
            o.x = keep * in[j].x + c * s.x;
            o.y = keep * in[j].y + c * s.y;
            o.z = keep * in[j].z + c * s.z;
            o.w = keep * in[j].w + c * s.w;
            __builtin_nontemporal_store(o, out + obase + (size_t)row * 160 + col);
        }
    }

    // ---- K phase: 64 rows x 32 f4 = 2048 f4 ----
    for (int t8 = 0; t8 < 2; ++t8) {
        f4 in[4];
        int idx[4];
        #pragma unroll
        for (int j = 0; j < 4; ++j) {
            idx[j] = t8 * 1024 + j * 256 + tid;
            in[j] = Kb[idx[j]];                     // cached: L3-hot from k_scores
        }
        #pragma unroll
        for (int j = 0; j < 4; ++j) {
            int row = idx[j] >> 5, col = idx[j] & 31;
            float c = scoef[row];
            f4 s = skv4[col];
            f4 o;
            o.x = keep * in[j].x + c * s.x;
            o.y = keep * in[j].y + c * s.y;
            o.z = keep * in[j].z + c * s.z;
            o.w = keep * in[j].w + c * s.w;
            __builtin_nontemporal_store(o, out + obase + (size_t)row * 160 + 128 + col);
        }
    }
}

extern "C" void kernel_launch(void* const* d_in, const int* in_sizes, int n_in,
                              void* d_out, int out_size, void* d_ws, size_t ws_size,
                              hipStream_t stream) {
    const float* s_t    = (const float*)d_in[0];
    const float* e_t    = (const float*)d_in[1];
    const float* ctx    = (const float*)d_in[2];
    const float* M      = (const float*)d_in[3];
    const float* K_mem  = (const float*)d_in[4];
    const float* decay  = (const float*)d_in[5];
    const float* W1_0   = (const float*)d_in[6];
    const float* b1_0   = (const float*)d_in[7];
    const float* W1_r   = (const float*)d_in[8];
    const float* b1_r   = (const float*)d_in[9];
    const float* spec_wr= (const float*)d_in[10];
    // d_in[11] = spec_wi: unused — irfft(n=1) keeps only the real part
    const float* ln_g   = (const float*)d_in[12];
    const float* ln_b   = (const float*)d_in[13];
    const float* Wg     = (const float*)d_in[14];
    const float* bg     = (const float*)d_in[15];
    const float* Wv     = (const float*)d_in[16];
    const float* bv     = (const float*)d_in[17];
    const float* Wk     = (const float*)d_in[18];
    const float* bk     = (const float*)d_in[19];

    float* ws = (float*)d_ws;
    float* expsc   = ws;                 // L*N            = 131072
    float* partial = ws + 131072;        // L*SB           = 2048
    float* ybuf    = ws + 133120;        // 512
    float* kvec    = ws + 133632;        // 512
    float* vvec    = ws + 134144;        // 2048
    float* wgt     = ws + 136192;        // 4
    float* keepb   = ws + 136196;        // 4

    dim3 gh(128, NLVL);
    k_h<<<gh, 256, 0, stream>>>(s_t, e_t, ctx, W1_0, b1_0, W1_r, b1_r,
                                spec_wr, ybuf);

    dim3 gzvk(10, NLVL);
    k_zvk<<<gzvk, 256, 0, stream>>>(ybuf, ln_g, ln_b, Wg, bg, decay,
                                    Wv, bv, Wk, bk, vvec, kvec, wgt, keepb);

    dim3 gs(SB, NLVL);
    k_scores<<<gs, 256, 0, stream>>>(K_mem, kvec, expsc, partial);

    k_write4<<<2048, 256, 0, stream>>>(M, K_mem, expsc, partial, wgt, keepb,
                                       vvec, kvec, (f4*)d_out);
}